// Round 7
// baseline (310.587 us; speedup 1.0000x reference)
//
#include <hip/hip_runtime.h>
#include <math.h>

#define DT 0.1f

typedef __attribute__((ext_vector_type(4)))  short short4v;
typedef __attribute__((ext_vector_type(8)))  short short8;
typedef __attribute__((ext_vector_type(16))) float f32x16;

__device__ __forceinline__ short f2bf(float x) {
    unsigned int u = __float_as_uint(x);
    unsigned int r = (u + 0x7fffu + ((u >> 16) & 1u)) >> 16;  // RNE
    return (short)r;
}
__device__ __forceinline__ float bf2f(short s) {
    return __uint_as_float(((unsigned int)(unsigned short)s) << 16);
}
__device__ __forceinline__ float tanh_fast(float x) {
    float e = __expf(x + x);
    float r = __builtin_amdgcn_rcpf(e + 1.f);
    return __builtin_fmaf(-2.f, r, 1.f);
}

// ---- packed B-fragment index for (k,n), 32x32x16 layout, KT = K/16 --------
// lane holds B[k = kt*16 + lh*8 + j][n = nt*32 + l31] at ((nt*KT+kt)*64+lane)*8+j
__device__ __forceinline__ int bfrag_idx(int k, int n, int KT) {
    int nt = n >> 5, l31 = n & 31;
    int kt = k >> 4, lh = (k >> 3) & 1, j = k & 7;
    return (((nt * KT + kt) * 64) + lh * 32 + l31) * 8 + j;
}

// ---- all 4 weight packs in one dispatch -----------------------------------
__global__ __launch_bounds__(256)
void packW(const float* __restrict__ W1, const float* __restrict__ W2,
           short* __restrict__ PB2, short* __restrict__ PB2T,
           short* __restrict__ PB1q, short* __restrict__ PB1Tp)
{
    int bx = blockIdx.x, tid = threadIdx.x;
    if (bx < 256) {                       // PB2 = W2 (K=256,N=256)
        int idx = bx * 256 + tid;
        int j = idx & 7, lane = (idx >> 3) & 63, rest = idx >> 9;
        int kt = rest % 16, nt = rest / 16;
        int k = kt * 16 + (lane >> 5) * 8 + j, n = nt * 32 + (lane & 31);
        PB2[idx] = f2bf(W2[k * 256 + n]);
    } else if (bx < 512) {                // PB2T = W2^T
        int idx = (bx - 256) * 256 + tid;
        int j = idx & 7, lane = (idx >> 3) & 63, rest = idx >> 9;
        int kt = rest % 16, nt = rest / 16;
        int k = kt * 16 + (lane >> 5) * 8 + j, n = nt * 32 + (lane & 31);
        PB2T[idx] = f2bf(W2[n * 256 + k]);
    } else if (bx < 1024) {               // PB1q = W1[:512,:] (K=512,N=256)
        int idx = (bx - 512) * 256 + tid;
        int j = idx & 7, lane = (idx >> 3) & 63, rest = idx >> 9;
        int kt = rest % 32, nt = rest / 32;
        int k = kt * 16 + (lane >> 5) * 8 + j, n = nt * 32 + (lane & 31);
        PB1q[idx] = f2bf(W1[k * 256 + n]);
    } else {                              // PB1Tp = W1p^T (K=256,N=512)
        int idx = (bx - 1024) * 256 + tid;
        int j = idx & 7, lane = (idx >> 3) & 63, rest = idx >> 9;
        int kt = rest % 16, nt = rest / 16;
        int k = kt * 16 + (lane >> 5) * 8 + j, n = nt * 32 + (lane & 31);
        PB1Tp[idx] = f2bf(W1[(512 + n) * 256 + k]);
    }
}

// ---- S matrices, 8 k-rows per block, packed output directly ---------------
// Sq = -dt/2 * W1q^T @ W1p   (for p-updates);  Sp = dt * W1p^T @ W1q
__global__ __launch_bounds__(256)
void compute_S_packed(const float* __restrict__ W1,
                      short* __restrict__ PBSq, short* __restrict__ PBSp)
{
    const int n = threadIdx.x;
    const int bx = blockIdx.x;
    const bool isp = bx >= 32;
    const int k0 = (isp ? bx - 32 : bx) * 8;
    float s[8] = {0.f, 0.f, 0.f, 0.f, 0.f, 0.f, 0.f, 0.f};
    const float* Wn = W1 + (isp ? 0 : 512 * 256);        // n-side half
    const float* Wk = W1 + (isp ? 512 * 256 : 0);        // k-side half
    for (int c = 0; c < 512; ++c) {
        float wn = Wn[c * 256 + n];
#pragma unroll
        for (int i = 0; i < 8; ++i)
            s[i] = __builtin_fmaf(Wk[c * 256 + k0 + i], wn, s[i]);
    }
    const float coef = isp ? DT : -0.5f * DT;
    short* dst = isp ? PBSp : PBSq;
#pragma unroll
    for (int i = 0; i < 8; ++i)
        dst[bfrag_idx(k0 + i, n, 16)] = f2bf(coef * s[i]);
}

// ---------------- LDS tile layout (verified R5/R6) -------------------------
__device__ __forceinline__ short8 lds_frag(const short* Ac, int kt, int mt2,
                                           int l31, int lh, int rot)
{
    int nt_s = kt >> 1;
    int po = (((kt & 1) * 2 + lh) * 4 + rot) & 15;
    int base = ((nt_s * 2 + mt2) * 64 + l31) * 16 + po;
    short4v x = *(const short4v*)&Ac[base];
    short4v y = *(const short4v*)&Ac[base + 512];
    short8 r;
    r[0] = x.x; r[1] = x.y; r[2] = x.z; r[3] = x.w;
    r[4] = y.x; r[5] = y.y; r[6] = y.z; r[7] = y.w;
    return r;
}
__device__ __forceinline__ void store_tile(short* Ac, int nt, int mt2, int lane,
                                           int rot, const f32x16 v)
{
    int base = ((nt * 2 + mt2) * 64 + lane) * 16;
#pragma unroll
    for (int c = 0; c < 4; ++c) {
        short4v pk;
        pk.x = f2bf(v[4 * c + 0]); pk.y = f2bf(v[4 * c + 1]);
        pk.z = f2bf(v[4 * c + 2]); pk.w = f2bf(v[4 * c + 3]);
        *(short4v*)&Ac[base + ((4 * c + rot) & 15)] = pk;
    }
}

// K=256 gemm, single 32x32 output tile: A (own mt) from LDS, B strip from L2.
__device__ __forceinline__ void gemm_nt1(const short* Ac, int mt, int l31, int lh,
                                         int rot, const short8* __restrict__ Bf,
                                         f32x16& acc)
{
    short8 pb[4];
#pragma unroll
    for (int k = 0; k < 4; ++k) pb[k] = Bf[k * 64];
    short8 pa = lds_frag(Ac, 0, mt, l31, lh, rot);
#pragma unroll
    for (int kt = 0; kt < 16; ++kt) {
        short8 ca = pa, cb = pb[kt & 3];
        if (kt + 4 < 16) pb[kt & 3] = Bf[(kt + 4) * 64];
        if (kt + 1 < 16) pa = lds_frag(Ac, kt + 1, mt, l31, lh, rot);
        acc = __builtin_amdgcn_mfma_f32_32x32x16_bf16(ca, cb, acc, 0, 0, 0);
    }
}

// ---------------- fused leapfrog: 256 blocks x 1024 thr, 16 waves ----------
// wave w: nt = w&7 (cols [32nt,32nt+32)), mt = w>>3 (rows [32mt,32mt+32))
__global__ __launch_bounds__(1024, 4)
void mega(const float* __restrict__ z,
          const short* __restrict__ PB1q,
          const short* __restrict__ PB2,
          const short* __restrict__ PB2T,
          const short* __restrict__ PBSq,
          const short* __restrict__ PBSp,
          const short* __restrict__ PB1Tp,
          const float* __restrict__ b1,
          const float* __restrict__ b2,
          const float* __restrict__ W3,
          float* __restrict__ out)
{
    __shared__ short smem[32768];        // h1_c | da_c ; also z-staging overlay
    short* const h1_c = smem;
    short* const da_c = smem + 16384;

    const int tid = threadIdx.x;
    const int lane = tid & 63, w = tid >> 6;
    const int nt = w & 7, mt = w >> 3;
    const int l31 = lane & 31, lh = lane >> 5;
    const int rot = ((l31 >> 2) & 3) * 4;
    const int bx = blockIdx.x;

    const int col = nt * 32 + l31;
    const float b1v = b1[col], b2v = b2[col], w3v = W3[col];

    f32x16 A1 = 0.f, dsum = 0.f;

    // ---- GEMM1: A1 = z @ W1q  (K=512, two LDS-staged 256-col chunks) ----
    {
        const short8* Bf = (const short8*)PB1q + ((size_t)nt * 32) * 64 + lane;
        const int m = mt * 32 + l31;
#pragma unroll
        for (int c = 0; c < 2; ++c) {
            // stage 64 rows x 256 cols (f32 -> bf16), XOR-swizzled 16B units
#pragma unroll
            for (int j = 0; j < 4; ++j) {
                int lin = j * 1024 + tid;
                int r = lin >> 6, c4 = lin & 63;
                float4 v = ((const float4*)z)[(size_t)(bx * 64 + r) * 128 + c * 64 + c4];
                short4v pk;
                pk.x = f2bf(v.x); pk.y = f2bf(v.y); pk.z = f2bf(v.z); pk.w = f2bf(v.w);
                int unit = (c4 >> 1) ^ (r & 31);
                *(short4v*)&smem[r * 256 + unit * 8 + (c4 & 1) * 4] = pk;
            }
            __syncthreads();
            short8 pb[4];
#pragma unroll
            for (int k = 0; k < 4; ++k) pb[k] = Bf[(c * 16 + k) * 64];
            short8 pa = *(const short8*)&smem[m * 256 + ((0 ^ (m & 31)) * 8)];
#pragma unroll
            for (int kt = 0; kt < 16; ++kt) {
                short8 ca = pa, cb = pb[kt & 3];
                if (kt + 4 < 16) pb[kt & 3] = Bf[(c * 16 + kt + 4) * 64];
                if (kt + 1 < 16) {
                    int unit = ((kt + 1) * 2 + lh) ^ (m & 31);
                    pa = *(const short8*)&smem[m * 256 + unit * 8];
                }
                A1 = __builtin_amdgcn_mfma_f32_32x32x16_bf16(ca, cb, A1, 0, 0, 0);
            }
            __syncthreads();
        }
    }

    const short8* PB2f  = (const short8*)PB2  + ((size_t)nt * 16) * 64 + lane;
    const short8* PB2Tf = (const short8*)PB2T + ((size_t)nt * 16) * 64 + lane;
    const short8* PBSqf = (const short8*)PBSq + ((size_t)nt * 16) * 64 + lane;
    const short8* PBSpf = (const short8*)PBSp + ((size_t)nt * 16) * 64 + lane;

    for (int it = 0; it < 8; ++it) {
        const bool isq = ((it % 3) == 1);

        // P1: h1 = tanh(A1 + b1)
        {
            f32x16 hv;
#pragma unroll
            for (int r = 0; r < 16; ++r) hv[r] = tanh_fast(A1[r] + b1v);
            store_tile(h1_c, nt, mt, lane, rot, hv);
        }
        __syncthreads();

        // P2: da2 = W3*(1-tanh^2(h1@W2 + b2))
        {
            f32x16 t0 = 0.f;
            gemm_nt1(h1_c, mt, l31, lh, rot, PB2f, t0);
            f32x16 d;
#pragma unroll
            for (int r = 0; r < 16; ++r) {
                float ta = tanh_fast(t0[r] + b2v);
                d[r] = w3v * (1.f - ta * ta);
            }
            store_tile(da_c, nt, mt, lane, rot, d);
        }
        __syncthreads();

        // P3: da1 = (da2@W2^T) * (1-h1^2)
        {
            f32x16 t0 = 0.f;
            gemm_nt1(da_c, mt, l31, lh, rot, PB2Tf, t0);
            float hv[16];
            const int basei = ((nt * 2 + mt) * 64 + lane) * 16;
#pragma unroll
            for (int c = 0; c < 4; ++c) {
                short4v h4 = *(const short4v*)&h1_c[basei + ((4 * c + rot) & 15)];
                hv[4 * c + 0] = bf2f(h4.x); hv[4 * c + 1] = bf2f(h4.y);
                hv[4 * c + 2] = bf2f(h4.z); hv[4 * c + 3] = bf2f(h4.w);
            }
            __syncthreads();   // all waves done gemm-reading da2 before overwrite
            f32x16 d;
#pragma unroll
            for (int r = 0; r < 16; ++r)
                d[r] = t0[r] * (1.f - hv[r] * hv[r]);
            if (isq) dsum += d;
            store_tile(da_c, nt, mt, lane, rot, d);
        }
        __syncthreads();

        // P4: A1 += da1 @ S (coef folded into S); skip after last q-update
        if (it < 7) {
            gemm_nt1(da_c, mt, l31, lh, rot, isq ? PBSpf : PBSqf, A1);
            // safe: P4 reads complete before this wave passes the next P1
            // barrier, which precedes any da_c overwrite.
        }
    }

    // ---- tail: out = z + dt * (dsum @ W1p^T), fused ----
    store_tile(da_c, nt, mt, lane, rot, dsum);
    __syncthreads();
    {
        const short8* Bo = (const short8*)PB1Tp + ((size_t)w * 16) * 64 + lane;
        f32x16 oc[2];
#pragma unroll
        for (int m2 = 0; m2 < 2; ++m2) {
            oc[m2] = 0.f;
            gemm_nt1(da_c, m2, l31, lh, rot, Bo, oc[m2]);
        }
#pragma unroll
        for (int m2 = 0; m2 < 2; ++m2) {
#pragma unroll
            for (int r = 0; r < 16; ++r) {
                int row = bx * 64 + m2 * 32 + (r & 3) + 8 * (r >> 2) + 4 * lh;
                size_t gi = (size_t)row * 512 + w * 32 + l31;
                out[gi] = z[gi] + DT * oc[m2][r];
            }
        }
    }
}

extern "C" void kernel_launch(void* const* d_in, const int* in_sizes, int n_in,
                              void* d_out, int out_size, void* d_ws, size_t ws_size,
                              hipStream_t stream)
{
    const float* z  = (const float*)d_in[0];
    const float* W1 = (const float*)d_in[1];   // 1024 x 256
    const float* b1 = (const float*)d_in[2];
    const float* W2 = (const float*)d_in[3];   // 256 x 256
    const float* b2 = (const float*)d_in[4];
    const float* W3 = (const float*)d_in[5];   // 256 x 1
    float* out = (float*)d_out;

    short* PBSq  = (short*)d_ws;               // 65536
    short* PBSp  = PBSq  + 65536;
    short* PB2   = PBSp  + 65536;
    short* PB2T  = PB2   + 65536;
    short* PB1q  = PB2T  + 65536;              // 131072 (K=512,N=256)
    short* PB1Tp = PB1q  + 131072;             // 131072 (K=256,N=512)

    compute_S_packed<<<64, 256, 0, stream>>>(W1, PBSq, PBSp);
    packW<<<1536, 256, 0, stream>>>(W1, W2, PB2, PB2T, PB1q, PB1Tp);
    mega<<<256, 1024, 0, stream>>>(z, PB1q, PB2, PB2T, PBSq, PBSp, PB1Tp,
                                   b1, b2, W3, out);
}